// Round 1
// baseline (4299.104 us; speedup 1.0000x reference)
//
#include <hip/hip_runtime.h>
#include <math.h>

#define FF 2048
#define NL 12
#define NB 16
#define TT 32
#define EPS 1e-5f

// ---------------------------------------------------------------------------
// Prepack kernel: fold l1_w (F,3)+l1_b(F) into float4 {w0,w1,w2,b} per f,
// and transpose l2_w (3,F) into float4 {u0,u1,u2,0} per f.
// Layout in d_ws: l1p[24][2048] float4, then l2p[24][2048] float4.
// Layers 0..11 = encoder, 12..23 = decoder.
// ---------------------------------------------------------------------------
__global__ __launch_bounds__(256) void prepack_kernel(
    const float* __restrict__ enc_l1_w, const float* __restrict__ enc_l1_b,
    const float* __restrict__ enc_l2_w,
    const float* __restrict__ dec_l1_w, const float* __restrict__ dec_l1_b,
    const float* __restrict__ dec_l2_w,
    float4* __restrict__ l1p, float4* __restrict__ l2p)
{
    int idx = blockIdx.x * blockDim.x + threadIdx.x;
    if (idx >= 24 * FF) return;
    int lay = idx >> 11;        // / 2048
    int f   = idx & (FF - 1);
    const float *w1, *b1, *w2;
    if (lay < NL) {
        w1 = enc_l1_w + (size_t)lay * FF * 3;
        b1 = enc_l1_b + (size_t)lay * FF;
        w2 = enc_l2_w + (size_t)lay * 3 * FF;
    } else {
        int l = lay - NL;
        w1 = dec_l1_w + (size_t)l * FF * 3;
        b1 = dec_l1_b + (size_t)l * FF;
        w2 = dec_l2_w + (size_t)l * 3 * FF;
    }
    l1p[idx] = make_float4(w1[f*3+0], w1[f*3+1], w1[f*3+2], b1[f]);
    l2p[idx] = make_float4(w2[f], w2[FF + f], w2[2*FF + f], 0.f);
}

// ---------------------------------------------------------------------------
// Main kernel: one block per batch element, 1024 threads (16 waves).
// ---------------------------------------------------------------------------
struct SharedMem {
    float x[TT][3];        // working activations (encoder x / decoder xw)
    float mem[TT][3];      // encoder output
    float outst[TT][3];    // decoder "out" state
    float qq[TT][3];
    float kk[TT][3];
    float vv[TT][3];
    float oo[TT][3];
    float ck[NL][TT][3];   // precomputed cross-attn keys per decoder layer
    float cv[NL][TT][3];   // precomputed cross-attn values
    float red[16][8][24];  // FFN partial-sum buffer [wave][lane/8][ii*3+d]
};

__device__ __forceinline__ void ln3(const float* y, const float* w,
                                    const float* b, float* out)
{
    float m  = (y[0] + y[1] + y[2]) * (1.0f / 3.0f);
    float d0 = y[0] - m, d1 = y[1] - m, d2 = y[2] - m;
    float v  = (d0*d0 + d1*d1 + d2*d2) * (1.0f / 3.0f);
    float r  = 1.0f / sqrtf(v + EPS);
    out[0] = d0 * r * w[0] + b[0];
    out[1] = d1 * r * w[1] + b[1];
    out[2] = d2 * r * w[2] + b[2];
}

// FFN body: 4 token-groups x 256 f-lanes. Group g owns tokens {g, g+4, ...}.
// Each thread handles 8 f's (f = flane + 256*j) for NII tokens.
template<int NII>
__device__ __forceinline__ void ffn_body(SharedMem& s, int tid,
        const float4* __restrict__ l1pg, const float4* __restrict__ l2pg)
{
    const int flane = tid & 255;
    const int g     = tid >> 8;
    const int lane  = tid & 63;
    const int wave  = tid >> 6;
    float xt[NII][3];
    float acc[NII][3];
    #pragma unroll
    for (int ii = 0; ii < NII; ii++) {
        const int t = g + 4*ii;
        xt[ii][0] = s.x[t][0];
        xt[ii][1] = s.x[t][1];
        xt[ii][2] = s.x[t][2];
        acc[ii][0] = 0.f; acc[ii][1] = 0.f; acc[ii][2] = 0.f;
    }
    #pragma unroll 4
    for (int j = 0; j < 8; j++) {
        const int f = flane + 256*j;
        const float4 a = l1pg[f];
        const float4 c = l2pg[f];
        #pragma unroll
        for (int ii = 0; ii < NII; ii++) {
            float h = fmaf(a.x, xt[ii][0],
                      fmaf(a.y, xt[ii][1],
                      fmaf(a.z, xt[ii][2], a.w)));
            h = fmaxf(h, 0.f);
            acc[ii][0] = fmaf(h, c.x, acc[ii][0]);
            acc[ii][1] = fmaf(h, c.y, acc[ii][1]);
            acc[ii][2] = fmaf(h, c.z, acc[ii][2]);
        }
    }
    // 3-step in-wave reduction (over groups of 8 consecutive flanes)
    #pragma unroll
    for (int ii = 0; ii < NII; ii++) {
        #pragma unroll
        for (int d = 0; d < 3; d++) {
            float v = acc[ii][d];
            v += __shfl_xor(v, 1);
            v += __shfl_xor(v, 2);
            v += __shfl_xor(v, 4);
            if ((lane & 7) == 0) s.red[wave][lane >> 3][ii*3 + d] = v;
        }
    }
}

// One transformer layer (self-attn [+cross-attn] + FFN), all in-block.
// rep: index of the zero-representative token (-1 if none); repw: its softmax
// multiplicity.
__device__ void run_layer(SharedMem& s, int tid, int ntok, int rep, float repw,
    const float* __restrict__ saw, const float* __restrict__ sab,
    const float* __restrict__ saow, const float* __restrict__ saob,
    const float* __restrict__ n1w, const float* __restrict__ n1b,
    int has_ca,
    const float* __restrict__ caw, const float* __restrict__ cab,
    const float* __restrict__ caow, const float* __restrict__ caob,
    const float* __restrict__ canw, const float* __restrict__ canb,
    const float (* __restrict__ ckl)[3], const float (* __restrict__ cvl)[3],
    const float4* __restrict__ l1pg, const float4* __restrict__ l2pg,
    const float* __restrict__ l2b,
    const float* __restrict__ nLw, const float* __restrict__ nLb)
{
    // ---- self-attention q,k,v (one thread per token)
    if (tid < ntok) {
        const float x0 = s.x[tid][0], x1 = s.x[tid][1], x2 = s.x[tid][2];
        #pragma unroll
        for (int h = 0; h < 3; h++) {
            s.qq[tid][h] = sab[h]   + saw[h*3]*x0      + saw[h*3+1]*x1      + saw[h*3+2]*x2;
            s.kk[tid][h] = sab[3+h] + saw[9+h*3]*x0    + saw[9+h*3+1]*x1    + saw[9+h*3+2]*x2;
            s.vv[tid][h] = sab[6+h] + saw[18+h*3]*x0   + saw[18+h*3+1]*x1   + saw[18+h*3+2]*x2;
        }
    }
    __syncthreads();
    // ---- self-attention softmax (head dim = 1, scale = 1); one thread per (q,h)
    if (tid < ntok * 3) {
        const int q = tid / 3;
        const int h = tid - q * 3;
        const float qv = s.qq[q][h];
        float mx = -1e30f;
        for (int j = 0; j < ntok; j++) mx = fmaxf(mx, qv * s.kk[j][h]);
        float den = 0.f, nv = 0.f;
        for (int j = 0; j < ntok; j++) {
            float w = __expf(fmaf(qv, s.kk[j][h], -mx));
            if (j == rep) w *= repw;   // zero-token multiplicity
            den += w;
            nv = fmaf(w, s.vv[j][h], nv);
        }
        s.oo[q][h] = nv / den;
    }
    __syncthreads();
    // ---- SA out-proj + residual + LN1
    if (tid < ntok) {
        float y[3];
        const float o0 = s.oo[tid][0], o1 = s.oo[tid][1], o2 = s.oo[tid][2];
        #pragma unroll
        for (int d = 0; d < 3; d++)
            y[d] = s.x[tid][d] + saob[d] + saow[d*3]*o0 + saow[d*3+1]*o1 + saow[d*3+2]*o2;
        ln3(y, n1w, n1b, s.x[tid]);
    }
    __syncthreads();
    if (has_ca) {
        // ---- cross-attention (keys/values precomputed from mem; full 32 keys)
        if (tid < ntok * 3) {
            const int q = tid / 3;
            const int h = tid - q * 3;
            const float* xr = s.x[q];
            const float qv = cab[h] + caw[h*3]*xr[0] + caw[h*3+1]*xr[1] + caw[h*3+2]*xr[2];
            float mx = -1e30f;
            for (int j = 0; j < TT; j++) mx = fmaxf(mx, qv * ckl[j][h]);
            float den = 0.f, nv = 0.f;
            for (int j = 0; j < TT; j++) {
                float w = __expf(fmaf(qv, ckl[j][h], -mx));
                den += w;
                nv = fmaf(w, cvl[j][h], nv);
            }
            s.oo[q][h] = nv / den;
        }
        __syncthreads();
        if (tid < ntok) {
            float y[3];
            const float o0 = s.oo[tid][0], o1 = s.oo[tid][1], o2 = s.oo[tid][2];
            #pragma unroll
            for (int d = 0; d < 3; d++)
                y[d] = s.x[tid][d] + caob[d] + caow[d*3]*o0 + caow[d*3+1]*o1 + caow[d*3+2]*o2;
            ln3(y, canw, canb, s.x[tid]);
        }
        __syncthreads();
    }
    // ---- FFN (3 -> 2048 -> 3, relu), token-group decomposition
    {
        const int g   = tid >> 8;
        const int nii = (ntok > g) ? (((ntok - 1 - g) >> 2) + 1) : 0;
        switch (nii) {
            case 8: ffn_body<8>(s, tid, l1pg, l2pg); break;
            case 7: ffn_body<7>(s, tid, l1pg, l2pg); break;
            case 6: ffn_body<6>(s, tid, l1pg, l2pg); break;
            case 5: ffn_body<5>(s, tid, l1pg, l2pg); break;
            case 4: ffn_body<4>(s, tid, l1pg, l2pg); break;
            case 3: ffn_body<3>(s, tid, l1pg, l2pg); break;
            case 2: ffn_body<2>(s, tid, l1pg, l2pg); break;
            case 1: ffn_body<1>(s, tid, l1pg, l2pg); break;
            default: break;
        }
    }
    __syncthreads();
    // ---- FFN combine + residual + final LN of the layer
    if (tid < ntok) {
        const int g2 = tid & 3;
        const int ii = tid >> 2;
        float s0 = 0.f, s1 = 0.f, s2 = 0.f;
        #pragma unroll
        for (int w = 0; w < 4; w++) {
            #pragma unroll
            for (int l = 0; l < 8; l++) {
                const float* r = s.red[4*g2 + w][l] + ii*3;
                s0 += r[0]; s1 += r[1]; s2 += r[2];
            }
        }
        float y[3] = { s.x[tid][0] + s0 + l2b[0],
                       s.x[tid][1] + s1 + l2b[1],
                       s.x[tid][2] + s2 + l2b[2] };
        ln3(y, nLw, nLb, s.x[tid]);
    }
    __syncthreads();
}

__global__ __launch_bounds__(1024) void seq_kernel(
    const float* __restrict__ src, const float* __restrict__ angle,
    const float* __restrict__ enc_sa_w, const float* __restrict__ enc_sa_b,
    const float* __restrict__ enc_sa_ow, const float* __restrict__ enc_sa_ob,
    const float* __restrict__ enc_l2_b,
    const float* __restrict__ enc_n1_w, const float* __restrict__ enc_n1_b,
    const float* __restrict__ enc_n2_w, const float* __restrict__ enc_n2_b,
    const float* __restrict__ enc_nf_w, const float* __restrict__ enc_nf_b,
    const float* __restrict__ dec_sa_w, const float* __restrict__ dec_sa_b,
    const float* __restrict__ dec_sa_ow, const float* __restrict__ dec_sa_ob,
    const float* __restrict__ dec_ca_w, const float* __restrict__ dec_ca_b,
    const float* __restrict__ dec_ca_ow, const float* __restrict__ dec_ca_ob,
    const float* __restrict__ dec_l2_b,
    const float* __restrict__ dec_n1_w, const float* __restrict__ dec_n1_b,
    const float* __restrict__ dec_n2_w, const float* __restrict__ dec_n2_b,
    const float* __restrict__ dec_n3_w, const float* __restrict__ dec_n3_b,
    const float* __restrict__ dec_nf_w, const float* __restrict__ dec_nf_b,
    const float4* __restrict__ l1p_all, const float4* __restrict__ l2p_all,
    float* __restrict__ out)
{
    __shared__ SharedMem s;
    const int tid = threadIdx.x;
    const int b   = blockIdx.x;

    // ---- build encoder input s[t] = (src[b,0,t], src[b,1,t], angle[b])
    if (tid < TT) {
        float x0 = src[b*64 + tid];
        float x1 = src[b*64 + 32 + tid];
        float x2 = angle[b];
        s.x[tid][0] = x0; s.x[tid][1] = x1; s.x[tid][2] = x2;
        if (tid == 0) { s.outst[0][0] = x0; s.outst[0][1] = x1; s.outst[0][2] = x2; }
    }
    __syncthreads();

    // ---- encoder: 12 layers, 32 real tokens
    for (int i = 0; i < NL; i++) {
        run_layer(s, tid, TT, -1, 1.0f,
                  enc_sa_w + i*27, enc_sa_b + i*9, enc_sa_ow + i*9, enc_sa_ob + i*3,
                  enc_n1_w + i*3, enc_n1_b + i*3,
                  0, nullptr, nullptr, nullptr, nullptr, nullptr, nullptr,
                  nullptr, nullptr,
                  l1p_all + i*FF, l2p_all + i*FF, enc_l2_b + i*3,
                  enc_n2_w + i*3, enc_n2_b + i*3);
    }
    // final encoder LN -> mem
    if (tid < TT) ln3(s.x[tid], enc_nf_w, enc_nf_b, s.mem[tid]);
    __syncthreads();

    // ---- precompute cross-attention K,V for all 12 decoder layers
    if (tid < NL * TT) {
        const int l = tid >> 5;
        const int t = tid & 31;
        const float* w  = dec_ca_w + l*27;
        const float* bb = dec_ca_b + l*9;
        const float* mr = s.mem[t];
        #pragma unroll
        for (int h = 0; h < 3; h++) {
            s.ck[l][t][h] = bb[3+h] + w[(3+h)*3]*mr[0] + w[(3+h)*3+1]*mr[1] + w[(3+h)*3+2]*mr[2];
            s.cv[l][t][h] = bb[6+h] + w[(6+h)*3]*mr[0] + w[(6+h)*3+1]*mr[1] + w[(6+h)*3+2]*mr[2];
        }
    }
    __syncthreads();

    // ---- autoregressive decode: steps t = 1..31.
    // Positions t..31 are all-zero and identical (no positional encoding), so we
    // process t real tokens + ONE zero-representative (index t) whose key gets
    // softmax multiplicity (32 - t). pred[t] == representative's output.
    for (int t = 1; t < TT; t++) {
        const int ntok = t + 1;
        if (tid <= t) {
            if (tid < t) {
                s.x[tid][0] = s.outst[tid][0];
                s.x[tid][1] = s.outst[tid][1];
                s.x[tid][2] = s.outst[tid][2];
            } else {
                s.x[tid][0] = 0.f; s.x[tid][1] = 0.f; s.x[tid][2] = 0.f;
            }
        }
        __syncthreads();
        for (int i = 0; i < NL; i++) {
            run_layer(s, tid, ntok, t, (float)(TT - t),
                      dec_sa_w + i*27, dec_sa_b + i*9, dec_sa_ow + i*9, dec_sa_ob + i*3,
                      dec_n1_w + i*3, dec_n1_b + i*3,
                      1, dec_ca_w + i*27, dec_ca_b + i*9, dec_ca_ow + i*9, dec_ca_ob + i*3,
                      dec_n2_w + i*3, dec_n2_b + i*3,
                      s.ck[i], s.cv[i],
                      l1p_all + (NL+i)*FF, l2p_all + (NL+i)*FF, dec_l2_b + i*3,
                      dec_n3_w + i*3, dec_n3_b + i*3);
        }
        if (tid == 0) ln3(s.x[t], dec_nf_w, dec_nf_b, s.outst[t]);
        __syncthreads();
    }

    // ---- write output: out[b, c, t] = outst[t][c]
    if (tid < TT) {
        #pragma unroll
        for (int c = 0; c < 3; c++)
            out[b*96 + c*32 + tid] = s.outst[tid][c];
    }
}

extern "C" void kernel_launch(void* const* d_in, const int* in_sizes, int n_in,
                              void* d_out, int out_size, void* d_ws, size_t ws_size,
                              hipStream_t stream) {
    const float* src      = (const float*)d_in[0];
    const float* angle    = (const float*)d_in[1];
    const float* enc_sa_w = (const float*)d_in[2];
    const float* enc_sa_b = (const float*)d_in[3];
    const float* enc_sa_ow= (const float*)d_in[4];
    const float* enc_sa_ob= (const float*)d_in[5];
    const float* enc_l1_w = (const float*)d_in[6];
    const float* enc_l1_b = (const float*)d_in[7];
    const float* enc_l2_w = (const float*)d_in[8];
    const float* enc_l2_b = (const float*)d_in[9];
    const float* enc_n1_w = (const float*)d_in[10];
    const float* enc_n1_b = (const float*)d_in[11];
    const float* enc_n2_w = (const float*)d_in[12];
    const float* enc_n2_b = (const float*)d_in[13];
    const float* enc_nf_w = (const float*)d_in[14];
    const float* enc_nf_b = (const float*)d_in[15];
    const float* dec_sa_w = (const float*)d_in[16];
    const float* dec_sa_b = (const float*)d_in[17];
    const float* dec_sa_ow= (const float*)d_in[18];
    const float* dec_sa_ob= (const float*)d_in[19];
    const float* dec_ca_w = (const float*)d_in[20];
    const float* dec_ca_b = (const float*)d_in[21];
    const float* dec_ca_ow= (const float*)d_in[22];
    const float* dec_ca_ob= (const float*)d_in[23];
    const float* dec_l1_w = (const float*)d_in[24];
    const float* dec_l1_b = (const float*)d_in[25];
    const float* dec_l2_w = (const float*)d_in[26];
    const float* dec_l2_b = (const float*)d_in[27];
    const float* dec_n1_w = (const float*)d_in[28];
    const float* dec_n1_b = (const float*)d_in[29];
    const float* dec_n2_w = (const float*)d_in[30];
    const float* dec_n2_b = (const float*)d_in[31];
    const float* dec_n3_w = (const float*)d_in[32];
    const float* dec_n3_b = (const float*)d_in[33];
    const float* dec_nf_w = (const float*)d_in[34];
    const float* dec_nf_b = (const float*)d_in[35];

    float4* l1p = (float4*)d_ws;
    float4* l2p = l1p + 24 * FF;

    prepack_kernel<<<(24 * FF + 255) / 256, 256, 0, stream>>>(
        enc_l1_w, enc_l1_b, enc_l2_w,
        dec_l1_w, dec_l1_b, dec_l2_w,
        l1p, l2p);

    seq_kernel<<<NB, 1024, 0, stream>>>(
        src, angle,
        enc_sa_w, enc_sa_b, enc_sa_ow, enc_sa_ob, enc_l2_b,
        enc_n1_w, enc_n1_b, enc_n2_w, enc_n2_b, enc_nf_w, enc_nf_b,
        dec_sa_w, dec_sa_b, dec_sa_ow, dec_sa_ob,
        dec_ca_w, dec_ca_b, dec_ca_ow, dec_ca_ob, dec_l2_b,
        dec_n1_w, dec_n1_b, dec_n2_w, dec_n2_b, dec_n3_w, dec_n3_b,
        dec_nf_w, dec_nf_b,
        (const float4*)l1p, (const float4*)l2p,
        (float*)d_out);
}

// Round 2
// 4064.841 us; speedup vs baseline: 1.0576x; 1.0576x over previous
//
#include <hip/hip_runtime.h>
#include <math.h>

#define FF 2048
#define NL 12
#define NB 16
#define TT 32
#define EPS 1e-5f

// ---------------------------------------------------------------------------
// Prepack kernel: fold l1_w (F,3)+l1_b(F) into float4 {w0,w1,w2,b} per f,
// and transpose l2_w (3,F) into float4 {u0,u1,u2,0} per f.
// Layout in d_ws: l1p[24][2048] float4, then l2p[24][2048] float4.
// Layers 0..11 = encoder, 12..23 = decoder.
// ---------------------------------------------------------------------------
__global__ __launch_bounds__(256) void prepack_kernel(
    const float* __restrict__ enc_l1_w, const float* __restrict__ enc_l1_b,
    const float* __restrict__ enc_l2_w,
    const float* __restrict__ dec_l1_w, const float* __restrict__ dec_l1_b,
    const float* __restrict__ dec_l2_w,
    float4* __restrict__ l1p, float4* __restrict__ l2p)
{
    int idx = blockIdx.x * blockDim.x + threadIdx.x;
    if (idx >= 24 * FF) return;
    int lay = idx >> 11;        // / 2048
    int f   = idx & (FF - 1);
    const float *w1, *b1, *w2;
    if (lay < NL) {
        w1 = enc_l1_w + (size_t)lay * FF * 3;
        b1 = enc_l1_b + (size_t)lay * FF;
        w2 = enc_l2_w + (size_t)lay * 3 * FF;
    } else {
        int l = lay - NL;
        w1 = dec_l1_w + (size_t)l * FF * 3;
        b1 = dec_l1_b + (size_t)l * FF;
        w2 = dec_l2_w + (size_t)l * 3 * FF;
    }
    l1p[idx] = make_float4(w1[f*3+0], w1[f*3+1], w1[f*3+2], b1[f]);
    l2p[idx] = make_float4(w2[f], w2[FF + f], w2[2*FF + f], 0.f);
}

// ---------------------------------------------------------------------------
// Main kernel: one block per batch element, 1024 threads (16 waves).
// ---------------------------------------------------------------------------
struct __align__(16) SharedMem {
    float x[TT][3];        // working activations
    float mem[TT][3];      // encoder output
    float outst[TT][3];    // decoder "out" state
    float kk[3][TT];       // self-attn keys, head-major (rows 16B-aligned)
    float vv[3][TT];       // self-attn values, head-major
    float oo[TT][3];       // attention output
    float ck[NL][3][TT];   // cross-attn keys per decoder layer, head-major
    float cv[NL][3][TT];   // cross-attn values
    float red[16][8][24];  // FFN partial-sum buffer [wave][lane/8][ii*3+d]
};

__device__ __forceinline__ void ln3(const float* y, const float* w,
                                    const float* b, float* out)
{
    float m  = (y[0] + y[1] + y[2]) * (1.0f / 3.0f);
    float d0 = y[0] - m, d1 = y[1] - m, d2 = y[2] - m;
    float v  = (d0*d0 + d1*d1 + d2*d2) * (1.0f / 3.0f);
    float r  = 1.0f / sqrtf(v + EPS);
    out[0] = d0 * r * w[0] + b[0];
    out[1] = d1 * r * w[1] + b[1];
    out[2] = d2 * r * w[2] + b[2];
}

// Unrolled masked softmax-attention for one (q, head):
// scores s_j = qv * k_j (head dim 1, scale 1); no max-subtraction (|s| < 5
// given LN-bounded activations and 0.1-scale weights -> exp can't overflow).
// j >= ntok masked to weight 0; j == rep gets multiplicity repw.
__device__ __forceinline__ float attn_row(float qv, const float* __restrict__ krow,
                                          const float* __restrict__ vrow,
                                          int ntok, int rep, float repw)
{
    const float4* k4 = (const float4*)krow;
    const float4* v4 = (const float4*)vrow;
    float den = 0.f, nv = 0.f;
    #pragma unroll
    for (int jb = 0; jb < 8; jb++) {
        const float4 kq = k4[jb];
        const float4 vq = v4[jb];
        const float kj[4] = {kq.x, kq.y, kq.z, kq.w};
        const float vj[4] = {vq.x, vq.y, vq.z, vq.w};
        #pragma unroll
        for (int u = 0; u < 4; u++) {
            const int j = jb * 4 + u;
            float w = __expf(qv * kj[u]);
            w = (j < ntok) ? w : 0.f;
            w = (j == rep) ? w * repw : w;
            den += w;
            nv = fmaf(w, vj[u], nv);
        }
    }
    return nv / den;
}

// One transformer layer (self-attn [+cross-attn] + FFN), all in-block.
template<int NII>
__device__ __forceinline__ void ffn_body(SharedMem& s, int tid,
        const float4* __restrict__ l1pg, const float4* __restrict__ l2pg)
{
    const int flane = tid & 255;
    const int g     = tid >> 8;
    const int lane  = tid & 63;
    const int wave  = tid >> 6;
    float xt[NII][3];
    float acc[NII][3];
    #pragma unroll
    for (int ii = 0; ii < NII; ii++) {
        const int t = g + 4*ii;
        xt[ii][0] = s.x[t][0];
        xt[ii][1] = s.x[t][1];
        xt[ii][2] = s.x[t][2];
        acc[ii][0] = 0.f; acc[ii][1] = 0.f; acc[ii][2] = 0.f;
    }
    #pragma unroll 4
    for (int j = 0; j < 8; j++) {
        const int f = flane + 256*j;
        const float4 a = l1pg[f];
        const float4 c = l2pg[f];
        #pragma unroll
        for (int ii = 0; ii < NII; ii++) {
            float h = fmaf(a.x, xt[ii][0],
                      fmaf(a.y, xt[ii][1],
                      fmaf(a.z, xt[ii][2], a.w)));
            h = fmaxf(h, 0.f);
            acc[ii][0] = fmaf(h, c.x, acc[ii][0]);
            acc[ii][1] = fmaf(h, c.y, acc[ii][1]);
            acc[ii][2] = fmaf(h, c.z, acc[ii][2]);
        }
    }
    #pragma unroll
    for (int ii = 0; ii < NII; ii++) {
        #pragma unroll
        for (int d = 0; d < 3; d++) {
            float v = acc[ii][d];
            v += __shfl_xor(v, 1);
            v += __shfl_xor(v, 2);
            v += __shfl_xor(v, 4);
            if ((lane & 7) == 0) s.red[wave][lane >> 3][ii*3 + d] = v;
        }
    }
}

__device__ void run_layer(SharedMem& s, int tid, int ntok, int rep, float repw,
    const float* __restrict__ saw, const float* __restrict__ sab,
    const float* __restrict__ saow, const float* __restrict__ saob,
    const float* __restrict__ n1w, const float* __restrict__ n1b,
    int has_ca,
    const float* __restrict__ caw, const float* __restrict__ cab,
    const float* __restrict__ caow, const float* __restrict__ caob,
    const float* __restrict__ canw, const float* __restrict__ canb,
    const float (* __restrict__ ckl)[TT], const float (* __restrict__ cvl)[TT],
    const float4* __restrict__ l1pg, const float4* __restrict__ l2pg,
    const float* __restrict__ l2b,
    const float* __restrict__ nLw, const float* __restrict__ nLb)
{
    // ---- stage A: self-attn k,v — one thread per (head, token)
    if (tid < 96) {
        const int hh = tid >> 5;
        const int t  = tid & 31;
        if (t < ntok) {
            const float* xr = s.x[t];
            s.kk[hh][t] = sab[3+hh] + saw[(3+hh)*3]*xr[0] + saw[(3+hh)*3+1]*xr[1] + saw[(3+hh)*3+2]*xr[2];
            s.vv[hh][t] = sab[6+hh] + saw[(6+hh)*3]*xr[0] + saw[(6+hh)*3+1]*xr[1] + saw[(6+hh)*3+2]*xr[2];
        }
    }
    __syncthreads();
    // ---- stage B: softmax-attention, q computed on the fly
    if (tid < 96) {
        const int hh = tid >> 5;
        const int q  = tid & 31;
        if (q < ntok) {
            const float* xr = s.x[q];
            const float qv = sab[hh] + saw[hh*3]*xr[0] + saw[hh*3+1]*xr[1] + saw[hh*3+2]*xr[2];
            s.oo[q][hh] = attn_row(qv, s.kk[hh], s.vv[hh], ntok, rep, repw);
        }
    }
    __syncthreads();
    // ---- stage C: SA out-proj + residual + LN1
    if (tid < ntok) {
        float y[3];
        const float o0 = s.oo[tid][0], o1 = s.oo[tid][1], o2 = s.oo[tid][2];
        #pragma unroll
        for (int d = 0; d < 3; d++)
            y[d] = s.x[tid][d] + saob[d] + saow[d*3]*o0 + saow[d*3+1]*o1 + saow[d*3+2]*o2;
        ln3(y, n1w, n1b, s.x[tid]);
    }
    __syncthreads();
    if (has_ca) {
        // ---- stage D: cross-attention (keys/values precomputed from mem)
        if (tid < 96) {
            const int hh = tid >> 5;
            const int q  = tid & 31;
            if (q < ntok) {
                const float* xr = s.x[q];
                const float qv = cab[hh] + caw[hh*3]*xr[0] + caw[hh*3+1]*xr[1] + caw[hh*3+2]*xr[2];
                s.oo[q][hh] = attn_row(qv, ckl[hh], cvl[hh], TT, -1, 1.0f);
            }
        }
        __syncthreads();
        // ---- stage E: CA out-proj + residual + LN2
        if (tid < ntok) {
            float y[3];
            const float o0 = s.oo[tid][0], o1 = s.oo[tid][1], o2 = s.oo[tid][2];
            #pragma unroll
            for (int d = 0; d < 3; d++)
                y[d] = s.x[tid][d] + caob[d] + caow[d*3]*o0 + caow[d*3+1]*o1 + caow[d*3+2]*o2;
            ln3(y, canw, canb, s.x[tid]);
        }
        __syncthreads();
    }
    // ---- FFN (3 -> 2048 -> 3, relu), token-group decomposition
    {
        const int g   = tid >> 8;
        const int nii = (ntok > g) ? (((ntok - 1 - g) >> 2) + 1) : 0;
        switch (nii) {
            case 8: ffn_body<8>(s, tid, l1pg, l2pg); break;
            case 7: ffn_body<7>(s, tid, l1pg, l2pg); break;
            case 6: ffn_body<6>(s, tid, l1pg, l2pg); break;
            case 5: ffn_body<5>(s, tid, l1pg, l2pg); break;
            case 4: ffn_body<4>(s, tid, l1pg, l2pg); break;
            case 3: ffn_body<3>(s, tid, l1pg, l2pg); break;
            case 2: ffn_body<2>(s, tid, l1pg, l2pg); break;
            case 1: ffn_body<1>(s, tid, l1pg, l2pg); break;
            default: break;
        }
    }
    __syncthreads();
    // ---- FFN combine + residual + final LN of the layer
    if (tid < ntok) {
        const int g2 = tid & 3;
        const int ii = tid >> 2;
        float s0 = 0.f, s1 = 0.f, s2 = 0.f;
        #pragma unroll
        for (int w = 0; w < 4; w++) {
            #pragma unroll
            for (int l = 0; l < 8; l++) {
                const float* r = s.red[4*g2 + w][l] + ii*3;
                s0 += r[0]; s1 += r[1]; s2 += r[2];
            }
        }
        float y[3] = { s.x[tid][0] + s0 + l2b[0],
                       s.x[tid][1] + s1 + l2b[1],
                       s.x[tid][2] + s2 + l2b[2] };
        ln3(y, nLw, nLb, s.x[tid]);
    }
    __syncthreads();
}

__global__ __launch_bounds__(1024) void seq_kernel(
    const float* __restrict__ src, const float* __restrict__ angle,
    const float* __restrict__ enc_sa_w, const float* __restrict__ enc_sa_b,
    const float* __restrict__ enc_sa_ow, const float* __restrict__ enc_sa_ob,
    const float* __restrict__ enc_l2_b,
    const float* __restrict__ enc_n1_w, const float* __restrict__ enc_n1_b,
    const float* __restrict__ enc_n2_w, const float* __restrict__ enc_n2_b,
    const float* __restrict__ enc_nf_w, const float* __restrict__ enc_nf_b,
    const float* __restrict__ dec_sa_w, const float* __restrict__ dec_sa_b,
    const float* __restrict__ dec_sa_ow, const float* __restrict__ dec_sa_ob,
    const float* __restrict__ dec_ca_w, const float* __restrict__ dec_ca_b,
    const float* __restrict__ dec_ca_ow, const float* __restrict__ dec_ca_ob,
    const float* __restrict__ dec_l2_b,
    const float* __restrict__ dec_n1_w, const float* __restrict__ dec_n1_b,
    const float* __restrict__ dec_n2_w, const float* __restrict__ dec_n2_b,
    const float* __restrict__ dec_n3_w, const float* __restrict__ dec_n3_b,
    const float* __restrict__ dec_nf_w, const float* __restrict__ dec_nf_b,
    const float4* __restrict__ l1p_all, const float4* __restrict__ l2p_all,
    float* __restrict__ out)
{
    __shared__ SharedMem s;
    const int tid = threadIdx.x;
    const int b   = blockIdx.x;

    // ---- build encoder input s[t] = (src[b,0,t], src[b,1,t], angle[b])
    if (tid < TT) {
        float x0 = src[b*64 + tid];
        float x1 = src[b*64 + 32 + tid];
        float x2 = angle[b];
        s.x[tid][0] = x0; s.x[tid][1] = x1; s.x[tid][2] = x2;
        if (tid == 0) { s.outst[0][0] = x0; s.outst[0][1] = x1; s.outst[0][2] = x2; }
    }
    __syncthreads();

    // ---- encoder: 12 layers, 32 real tokens
    for (int i = 0; i < NL; i++) {
        run_layer(s, tid, TT, -1, 1.0f,
                  enc_sa_w + i*27, enc_sa_b + i*9, enc_sa_ow + i*9, enc_sa_ob + i*3,
                  enc_n1_w + i*3, enc_n1_b + i*3,
                  0, nullptr, nullptr, nullptr, nullptr, nullptr, nullptr,
                  nullptr, nullptr,
                  l1p_all + i*FF, l2p_all + i*FF, enc_l2_b + i*3,
                  enc_n2_w + i*3, enc_n2_b + i*3);
    }
    // final encoder LN -> mem
    if (tid < TT) ln3(s.x[tid], enc_nf_w, enc_nf_b, s.mem[tid]);
    __syncthreads();

    // ---- precompute cross-attention K,V for all 12 decoder layers (head-major)
    for (int idx = tid; idx < NL * 96; idx += 1024) {
        const int l  = idx / 96;
        const int r  = idx - l * 96;
        const int hh = r >> 5;
        const int t  = r & 31;
        const float* w  = dec_ca_w + l*27;
        const float* bb = dec_ca_b + l*9;
        const float* mr = s.mem[t];
        s.ck[l][hh][t] = bb[3+hh] + w[(3+hh)*3]*mr[0] + w[(3+hh)*3+1]*mr[1] + w[(3+hh)*3+2]*mr[2];
        s.cv[l][hh][t] = bb[6+hh] + w[(6+hh)*3]*mr[0] + w[(6+hh)*3+1]*mr[1] + w[(6+hh)*3+2]*mr[2];
    }
    __syncthreads();

    // ---- autoregressive decode: steps t = 1..31.
    // Positions t..31 are all-zero and identical (no positional encoding), so we
    // process t real tokens + ONE zero-representative (index t) whose key gets
    // softmax multiplicity (32 - t). pred[t] == representative's output.
    for (int t = 1; t < TT; t++) {
        const int ntok = t + 1;
        if (tid <= t) {
            if (tid < t) {
                s.x[tid][0] = s.outst[tid][0];
                s.x[tid][1] = s.outst[tid][1];
                s.x[tid][2] = s.outst[tid][2];
            } else {
                s.x[tid][0] = 0.f; s.x[tid][1] = 0.f; s.x[tid][2] = 0.f;
            }
        }
        __syncthreads();
        for (int i = 0; i < NL; i++) {
            run_layer(s, tid, ntok, t, (float)(TT - t),
                      dec_sa_w + i*27, dec_sa_b + i*9, dec_sa_ow + i*9, dec_sa_ob + i*3,
                      dec_n1_w + i*3, dec_n1_b + i*3,
                      1, dec_ca_w + i*27, dec_ca_b + i*9, dec_ca_ow + i*9, dec_ca_ob + i*3,
                      dec_n2_w + i*3, dec_n2_b + i*3,
                      s.ck[i], s.cv[i],
                      l1p_all + (NL+i)*FF, l2p_all + (NL+i)*FF, dec_l2_b + i*3,
                      dec_n3_w + i*3, dec_n3_b + i*3);
        }
        if (tid == 0) ln3(s.x[t], dec_nf_w, dec_nf_b, s.outst[t]);
        __syncthreads();
    }

    // ---- write output: out[b, c, t] = outst[t][c]
    if (tid < TT) {
        #pragma unroll
        for (int c = 0; c < 3; c++)
            out[b*96 + c*32 + tid] = s.outst[tid][c];
    }
}

extern "C" void kernel_launch(void* const* d_in, const int* in_sizes, int n_in,
                              void* d_out, int out_size, void* d_ws, size_t ws_size,
                              hipStream_t stream) {
    const float* src      = (const float*)d_in[0];
    const float* angle    = (const float*)d_in[1];
    const float* enc_sa_w = (const float*)d_in[2];
    const float* enc_sa_b = (const float*)d_in[3];
    const float* enc_sa_ow= (const float*)d_in[4];
    const float* enc_sa_ob= (const float*)d_in[5];
    const float* enc_l1_w = (const float*)d_in[6];
    const float* enc_l1_b = (const float*)d_in[7];
    const float* enc_l2_w = (const float*)d_in[8];
    const float* enc_l2_b = (const float*)d_in[9];
    const float* enc_n1_w = (const float*)d_in[10];
    const float* enc_n1_b = (const float*)d_in[11];
    const float* enc_n2_w = (const float*)d_in[12];
    const float* enc_n2_b = (const float*)d_in[13];
    const float* enc_nf_w = (const float*)d_in[14];
    const float* enc_nf_b = (const float*)d_in[15];
    const float* dec_sa_w = (const float*)d_in[16];
    const float* dec_sa_b = (const float*)d_in[17];
    const float* dec_sa_ow= (const float*)d_in[18];
    const float* dec_sa_ob= (const float*)d_in[19];
    const float* dec_ca_w = (const float*)d_in[20];
    const float* dec_ca_b = (const float*)d_in[21];
    const float* dec_ca_ow= (const float*)d_in[22];
    const float* dec_ca_ob= (const float*)d_in[23];
    const float* dec_l1_w = (const float*)d_in[24];
    const float* dec_l1_b = (const float*)d_in[25];
    const float* dec_l2_w = (const float*)d_in[26];
    const float* dec_l2_b = (const float*)d_in[27];
    const float* dec_n1_w = (const float*)d_in[28];
    const float* dec_n1_b = (const float*)d_in[29];
    const float* dec_n2_w = (const float*)d_in[30];
    const float* dec_n2_b = (const float*)d_in[31];
    const float* dec_n3_w = (const float*)d_in[32];
    const float* dec_n3_b = (const float*)d_in[33];
    const float* dec_nf_w = (const float*)d_in[34];
    const float* dec_nf_b = (const float*)d_in[35];

    float4* l1p = (float4*)d_ws;
    float4* l2p = l1p + 24 * FF;

    prepack_kernel<<<(24 * FF + 255) / 256, 256, 0, stream>>>(
        enc_l1_w, enc_l1_b, enc_l2_w,
        dec_l1_w, dec_l1_b, dec_l2_w,
        l1p, l2p);

    seq_kernel<<<NB, 1024, 0, stream>>>(
        src, angle,
        enc_sa_w, enc_sa_b, enc_sa_ow, enc_sa_ob, enc_l2_b,
        enc_n1_w, enc_n1_b, enc_n2_w, enc_n2_b, enc_nf_w, enc_nf_b,
        dec_sa_w, dec_sa_b, dec_sa_ow, dec_sa_ob,
        dec_ca_w, dec_ca_b, dec_ca_ow, dec_ca_ob, dec_l2_b,
        dec_n1_w, dec_n1_b, dec_n2_w, dec_n2_b, dec_n3_w, dec_n3_b,
        dec_nf_w, dec_nf_b,
        (const float4*)l1p, (const float4*)l2p,
        (float*)d_out);
}